// Round 10
// baseline (125774.585 us; speedup 1.0000x reference)
//
#include <hip/hip_runtime.h>

#define S_LEN 65536
#define HDIM 128

typedef _Float16 half2_t __attribute__((ext_vector_type(2)));
typedef _Float16 half4_t __attribute__((ext_vector_type(4)));
typedef _Float16 half8_t __attribute__((ext_vector_type(8)));
typedef float f32x4 __attribute__((ext_vector_type(4)));

__device__ __forceinline__ float sigm(float x) {
    return 1.0f / (1.0f + __expf(-x));
}
__device__ __forceinline__ float tanh_fast(float x) {
    return 2.0f / (1.0f + __expf(-2.0f * x)) - 1.0f;
}
__device__ __forceinline__ float dot2(half2_t a, half2_t b, float c) {
#if __has_builtin(__builtin_amdgcn_fdot2)
    return __builtin_amdgcn_fdot2(a, b, c, false);
#else
    return fmaf((float)a.x, (float)b.x, fmaf((float)a.y, (float)b.y, c));
#endif
}

// lgkmcnt-only barrier (validated correct in R9).
__device__ __forceinline__ void block_sync_lds() {
    asm volatile("s_waitcnt lgkmcnt(0)" ::: "memory");
    __builtin_amdgcn_s_barrier();
}

// ================= Kernel 1: MFMA recurrence, in-place phase B =============
// R9 post-mortem: 1650 cyc/step = ~620 MFMA-pipe (structural 16x matvec
// waste) + ~400 serial phase-B span (gates LDS round-trip + 2-wave
// serialization) + 2 barriers. This round: wave w's 4 tiles = gates i,f,g,o
// for rows [16w,16w+16)  ->  after MFMA, lane(quad,m==0) reg r holds all 4
// gates of row 16w+4q+r in acc0..acc3 at the same position. Phase B runs
// in-register on those lanes; xg+bias folds into the MFMA C-init; h
// ping-pongs through LDS; ONE barrier per step.
__global__ __launch_bounds__(512)
__attribute__((amdgpu_waves_per_eu(2, 2)))
void lstm_seq_mfma(const float* __restrict__ x,
                   const float* __restrict__ h0,
                   const float* __restrict__ c0,
                   const float* __restrict__ W_ih,
                   const float* __restrict__ W_hh,
                   const float* __restrict__ b_ih,
                   const float* __restrict__ b_hh,
                   _Float16* __restrict__ h_hist)
{
    __shared__ __align__(16) _Float16 hbuf[2][HDIM];   // ping-pong h_t

    const int tid  = threadIdx.x;       // 0..511, 8 waves
    const int lane = tid & 63;
    const int w    = tid >> 6;          // wave id: rows-within-gate [16w,16w+16)
    const int m    = lane & 15;         // A row within tile / D col
    const int quad = lane >> 4;         // 0..3

    // ---- A fragments: tile g = gate g, rows g*128 + 16w + m ----
    // A[m][k=(lane>>4)*8+j], k-chunk kc covers k in [32kc, 32kc+32).
#define LOAD_AF(g, kc) \
    half8_t af_##g##_##kc; { \
        const float* s_ = W_hh + (size_t)((g) * 128 + 16 * w + m) * HDIM \
                               + 32 * (kc) + 8 * quad; \
        af_##g##_##kc = (half8_t){ \
            (_Float16)s_[0], (_Float16)s_[1], (_Float16)s_[2], (_Float16)s_[3], \
            (_Float16)s_[4], (_Float16)s_[5], (_Float16)s_[6], (_Float16)s_[7] }; \
        asm volatile("" : "+v"(af_##g##_##kc)); }
    LOAD_AF(0, 0) LOAD_AF(0, 1) LOAD_AF(0, 2) LOAD_AF(0, 3)
    LOAD_AF(1, 0) LOAD_AF(1, 1) LOAD_AF(1, 2) LOAD_AF(1, 3)
    LOAD_AF(2, 0) LOAD_AF(2, 1) LOAD_AF(2, 2) LOAD_AF(2, 3)
    LOAD_AF(3, 0) LOAD_AF(3, 1) LOAD_AF(3, 2) LOAD_AF(3, 3)
#undef LOAD_AF

    // ---- Phase-B constants: rows base+r, base = 16w+4q (m==0 lanes only;
    // zeros elsewhere so the uniform xg-init computes 0 harmlessly). ----
    const int base = 16 * w + 4 * quad;
#define PBC(g) \
    f32x4 wx##g = {0,0,0,0}, wy##g = {0,0,0,0}, bs##g = {0,0,0,0}; \
    if (m == 0) { \
        _Pragma("unroll") \
        for (int r = 0; r < 4; ++r) { \
            int row = (g) * 128 + base + r; \
            wx##g[r] = W_ih[2 * row]; \
            wy##g[r] = W_ih[2 * row + 1]; \
            bs##g[r] = b_ih[row] + b_hh[row]; \
        } \
        asm volatile("" : "+v"(wx##g), "+v"(wy##g), "+v"(bs##g)); \
    }
    PBC(0) PBC(1) PBC(2) PBC(3)
#undef PBC

    // c state: rows base+r (m==0 lanes)
    f32x4 c = {0, 0, 0, 0};
    if (m == 0) {
        #pragma unroll
        for (int r = 0; r < 4; ++r) c[r] = c0[base + r];
    }

    if (tid < HDIM) hbuf[0][tid] = (_Float16)h0[tid];
    __syncthreads();   // once, pre-loop

    const float2* xp = (const float2*)x;
    float2 xcur = xp[0];   // wave-uniform (all waves load their own copy)

    half8_t bf0 = (half8_t){0,0,0,0,0,0,0,0};
    half8_t bf1 = bf0, bf2 = bf0, bf3 = bf0;

    #pragma unroll 1
    for (int t = 0; t < S_LEN; ++t) {
        const int p = t & 1;
        const int tn = (t + 1 < S_LEN) ? (t + 1) : (S_LEN - 1);
        float2 xnext = xp[tn];   // prefetch

        // ---- B fragments: col 0 = h, lanes {0,16,32,48} ----
        if (m == 0) {
            const half8_t* hb = (const half8_t*)hbuf[p];
            bf0 = hb[quad];
            bf1 = hb[4 + quad];
            bf2 = hb[8 + quad];
            bf3 = hb[12 + quad];
        }

        // ---- C init = xg + bias (uniform; non-owner lanes compute 0) ----
        f32x4 acc0, acc1, acc2, acc3;
        #pragma unroll
        for (int r = 0; r < 4; ++r) {
            acc0[r] = fmaf(wx0[r], xcur.x, fmaf(wy0[r], xcur.y, bs0[r]));
            acc1[r] = fmaf(wx1[r], xcur.x, fmaf(wy1[r], xcur.y, bs1[r]));
            acc2[r] = fmaf(wx2[r], xcur.x, fmaf(wy2[r], xcur.y, bs2[r]));
            acc3[r] = fmaf(wx3[r], xcur.x, fmaf(wy3[r], xcur.y, bs3[r]));
        }

#define MFMA_TILE(g) \
        acc##g = __builtin_amdgcn_mfma_f32_16x16x32_f16(af_##g##_0, bf0, acc##g, 0, 0, 0); \
        acc##g = __builtin_amdgcn_mfma_f32_16x16x32_f16(af_##g##_1, bf1, acc##g, 0, 0, 0); \
        acc##g = __builtin_amdgcn_mfma_f32_16x16x32_f16(af_##g##_2, bf2, acc##g, 0, 0, 0); \
        acc##g = __builtin_amdgcn_mfma_f32_16x16x32_f16(af_##g##_3, bf3, acc##g, 0, 0, 0);
        MFMA_TILE(0) MFMA_TILE(1) MFMA_TILE(2) MFMA_TILE(3)
#undef MFMA_TILE

        // ---- Phase B in-register (meaningful on m==0 lanes; uniform) ----
        half4_t hv4;
        #pragma unroll
        for (int r = 0; r < 4; ++r) {
            float gi = sigm(acc0[r]);
            float gf = sigm(acc1[r]);
            float gg = tanh_fast(acc2[r]);
            float go = sigm(acc3[r]);
            c[r] = fmaf(gf, c[r], gi * gg);
            hv4[r] = (_Float16)(go * tanh_fast(c[r]));
        }
        if (m == 0) {
            *(half4_t*)&hbuf[1 - p][base] = hv4;              // next step's h
            *(half4_t*)(h_hist + (size_t)t * HDIM + base) = hv4;  // floats past barrier
        }

        xcur = xnext;
        block_sync_lds();   // ONE barrier: h_{t} writes visible for t+1 reads
    }
}

// ================= Kernel 2: out[t] = tanh(h_t).W_out + b =================
__global__ __launch_bounds__(256)
void out_proj(const _Float16* __restrict__ h_hist,
              const float* __restrict__ W_out,
              const float* __restrict__ b_out,
              float* __restrict__ out)
{
    const int lane  = threadIdx.x & 63;
    const int gwave = (blockIdx.x * 256 + threadIdx.x) >> 6;
    const int nwave = (gridDim.x * 256) >> 6;

    const float wo0 = W_out[2 * lane + 0];
    const float wo1 = W_out[2 * lane + 1];
    const float bout = b_out[0];

    for (int t = gwave; t < S_LEN; t += nwave) {
        half2_t hv = ((const half2_t*)(h_hist + (size_t)t * HDIM))[lane];
        float p = tanh_fast((float)hv.x) * wo0 + tanh_fast((float)hv.y) * wo1;
        #pragma unroll
        for (int off = 32; off > 0; off >>= 1)
            p += __shfl_xor(p, off, 64);
        if (lane == 0) out[t] = p + bout;
    }
}

// ================= Fallback: fused single kernel (ws too small) ===========
#define H_HI_OFF 144
__global__ __launch_bounds__(1024)
__attribute__((amdgpu_waves_per_eu(4, 4)))
void lstm_seq_full(const float* __restrict__ x,
                   const float* __restrict__ h0,
                   const float* __restrict__ c0,
                   const float* __restrict__ W_ih,
                   const float* __restrict__ W_hh,
                   const float* __restrict__ b_ih,
                   const float* __restrict__ b_hh,
                   const float* __restrict__ W_out,
                   const float* __restrict__ b_out,
                   float* __restrict__ out)
{
    __shared__ __align__(16) unsigned char h_raw[2 * H_HI_OFF];
    __shared__ float gates_part[2 * 512];
    __shared__ float red_sh[2];

    const int tid  = threadIdx.x;
    const int j    = tid >> 1;
    const int half = tid & 1;

    const float2* wr2 = (const float2*)(W_hh + j * HDIM + half * 64);
#define WDEF(i) half2_t W##i; { float2 t = wr2[i]; \
        W##i.x = (_Float16)t.x; W##i.y = (_Float16)t.y; } \
        asm volatile("" : "+v"(W##i));
    WDEF(0)  WDEF(1)  WDEF(2)  WDEF(3)  WDEF(4)  WDEF(5)  WDEF(6)  WDEF(7)
    WDEF(8)  WDEF(9)  WDEF(10) WDEF(11) WDEF(12) WDEF(13) WDEF(14) WDEF(15)
    WDEF(16) WDEF(17) WDEF(18) WDEF(19) WDEF(20) WDEF(21) WDEF(22) WDEF(23)
    WDEF(24) WDEF(25) WDEF(26) WDEF(27) WDEF(28) WDEF(29) WDEF(30) WDEF(31)
#undef WDEF

    float wih0 = 0.0f, wih1 = 0.0f, bias = 0.0f;
    if (half == 0) {
        wih0 = W_ih[2 * j + 0];
        wih1 = W_ih[2 * j + 1];
        bias = b_ih[j] + b_hh[j];
    }

    float c = 0.0f, wout = 0.0f;
    _Float16* hw = (_Float16*)(h_raw + ((tid < 64) ? 2 * tid
                                                   : H_HI_OFF + 2 * (tid - 64)));
    if (tid < HDIM) {
        c = c0[tid];
        wout = W_out[tid];
        *hw = (_Float16)h0[tid];
    }
    const float bout = b_out[0];
    __syncthreads();

    const float2* xp = (const float2*)x;
    float2 xcur = xp[0];
    const half8_t* hp = (const half8_t*)(h_raw + half * H_HI_OFF);

    #pragma unroll 1
    for (int t = 0; t < S_LEN; ++t) {
        const int tn = (t + 1 < S_LEN) ? (t + 1) : (S_LEN - 1);
        float2 xnext = xp[tn];

        float a0 = fmaf(wih0, xcur.x, fmaf(wih1, xcur.y, bias));
        float a1 = 0.0f, a2 = 0.0f, a3 = 0.0f;

#define CHUNK(cc, w0_, w1_, w2_, w3_) {                         \
        half8_t hv = hp[cc];                                    \
        half2_t p0 = { hv[0], hv[1] };                          \
        half2_t p1 = { hv[2], hv[3] };                          \
        half2_t p2 = { hv[4], hv[5] };                          \
        half2_t p3 = { hv[6], hv[7] };                          \
        a0 = dot2(w0_, p0, a0);                                 \
        a1 = dot2(w1_, p1, a1);                                 \
        a2 = dot2(w2_, p2, a2);                                 \
        a3 = dot2(w3_, p3, a3); }
        CHUNK(0, W0,  W1,  W2,  W3)
        CHUNK(1, W4,  W5,  W6,  W7)
        CHUNK(2, W8,  W9,  W10, W11)
        CHUNK(3, W12, W13, W14, W15)
        CHUNK(4, W16, W17, W18, W19)
        CHUNK(5, W20, W21, W22, W23)
        CHUNK(6, W24, W25, W26, W27)
        CHUNK(7, W28, W29, W30, W31)
#undef CHUNK

        gates_part[half * 512 + j] = (a0 + a1) + (a2 + a3);
        __syncthreads();

        if (tid < HDIM) {
            float gi = sigm(gates_part[tid]            + gates_part[tid + 512]);
            float gf = sigm(gates_part[tid + 128]      + gates_part[tid + 640]);
            float gg = tanh_fast(gates_part[tid + 256] + gates_part[tid + 768]);
            float go = sigm(gates_part[tid + 384]      + gates_part[tid + 896]);
            c = fmaf(gf, c, gi * gg);
            float h = go * tanh_fast(c);
            *hw = (_Float16)h;

            float p = tanh_fast(h) * wout;
            #pragma unroll
            for (int off = 32; off > 0; off >>= 1)
                p += __shfl_xor(p, off, 64);
            if ((tid & 63) == 0) red_sh[tid >> 6] = p;
        }
        __syncthreads();

        if (tid == 0) out[t] = red_sh[0] + red_sh[1] + bout;
        xcur = xnext;
    }
}

extern "C" void kernel_launch(void* const* d_in, const int* in_sizes, int n_in,
                              void* d_out, int out_size, void* d_ws, size_t ws_size,
                              hipStream_t stream) {
    const float* x     = (const float*)d_in[0];
    const float* h0    = (const float*)d_in[1];
    const float* c0    = (const float*)d_in[2];
    const float* W_ih  = (const float*)d_in[3];
    const float* W_hh  = (const float*)d_in[4];
    const float* b_ih  = (const float*)d_in[5];
    const float* b_hh  = (const float*)d_in[6];
    const float* W_out = (const float*)d_in[7];
    const float* b_out = (const float*)d_in[8];

    const size_t need = (size_t)S_LEN * HDIM * sizeof(_Float16);  // 16 MiB
    if (ws_size >= need) {
        _Float16* h_hist = (_Float16*)d_ws;
        lstm_seq_mfma<<<dim3(1), dim3(512), 0, stream>>>(
            x, h0, c0, W_ih, W_hh, b_ih, b_hh, h_hist);
        out_proj<<<dim3(1024), dim3(256), 0, stream>>>(
            h_hist, W_out, b_out, (float*)d_out);
    } else {
        lstm_seq_full<<<dim3(1), dim3(1024), 0, stream>>>(
            x, h0, c0, W_ih, W_hh, b_ih, b_hh, W_out, b_out, (float*)d_out);
    }
}

// Round 11
// 44561.386 us; speedup vs baseline: 2.8225x; 2.8225x over previous
//
#include <hip/hip_runtime.h>

#define S_LEN 65536
#define HDIM 128

typedef _Float16 half2_t __attribute__((ext_vector_type(2)));
typedef _Float16 half8_t __attribute__((ext_vector_type(8)));
typedef float f32x4 __attribute__((ext_vector_type(4)));

__device__ __forceinline__ float sigm(float x) {
    return 1.0f / (1.0f + __expf(-x));
}
__device__ __forceinline__ float tanh_fast(float x) {
    return 2.0f / (1.0f + __expf(-2.0f * x)) - 1.0f;
}
__device__ __forceinline__ float dot2(half2_t a, half2_t b, float c) {
#if __has_builtin(__builtin_amdgcn_fdot2)
    return __builtin_amdgcn_fdot2(a, b, c, false);
#else
    return fmaf((float)a.x, (float)b.x, fmaf((float)a.y, (float)b.y, c));
#endif
}

// lgkmcnt-only barrier (validated correct + fast in R9).
__device__ __forceinline__ void block_sync_lds() {
    asm volatile("s_waitcnt lgkmcnt(0)" ::: "memory");
    __builtin_amdgcn_s_barrier();
}

// ================= Kernel 1: MFMA recurrence (R9 skeleton) ================
// R10 post-mortem: in-place phase B spilled (88 VGPR vs ~150 demand) and ran
// 16 transcendental chains per wave-stream on all 8 waves (VALUBusy 0.23).
// R11: R9's MFMA/A-frag/B-frag structure verbatim; phase B spread across all
// 512 threads at ONE gate-row each (thread 4r+g -> gate g, row r):
//  - gates stored row-major [row][gate] -> consumer read = gates_sh[tid],
//    conflict-free; producer writes 4x b32 (2-way banks, free).
//  - per-thread xg+bias fold (3 regs), branchless sigm/tanh
//    (v=1/(1+exp(-s*x)), act=s*v+(1-s); s=2 for gate 2 else 1).
//  - quad combine via __shfl_xor 1,2 (intra-quad); g==0 lanes (128) do the
//    c-update + final tanh + h write.
__global__ __launch_bounds__(512)
__attribute__((amdgpu_waves_per_eu(2, 2)))
void lstm_seq_mfma(const float* __restrict__ x,
                   const float* __restrict__ h0,
                   const float* __restrict__ c0,
                   const float* __restrict__ W_ih,
                   const float* __restrict__ W_hh,
                   const float* __restrict__ b_ih,
                   const float* __restrict__ b_hh,
                   _Float16* __restrict__ h_hist)
{
    __shared__ __align__(16) _Float16 hbuf[2][HDIM];   // ping-pong h_t
    __shared__ __align__(16) float gates_sh[4 * HDIM]; // addr = row*4 + gate

    const int tid  = threadIdx.x;       // 0..511, 8 waves
    const int lane = tid & 63;
    const int w    = tid >> 6;          // wave id 0..7: gate-rows [w*64, w*64+64)
    const int m    = lane & 15;         // A-fragment row within tile
    const int quad = lane >> 4;         // 0..3

    // ---- A fragments (R9-verbatim): tile i rows w*64+16i+m ----
#define LOAD_AF(i, q) \
    half8_t af_##i##_##q; { \
        const float* s_ = W_hh + (size_t)(w * 64 + 16 * (i) + m) * HDIM \
                               + 32 * (q) + 8 * quad; \
        af_##i##_##q = (half8_t){ \
            (_Float16)s_[0], (_Float16)s_[1], (_Float16)s_[2], (_Float16)s_[3], \
            (_Float16)s_[4], (_Float16)s_[5], (_Float16)s_[6], (_Float16)s_[7] }; \
        asm volatile("" : "+v"(af_##i##_##q)); }
    LOAD_AF(0, 0) LOAD_AF(0, 1) LOAD_AF(0, 2) LOAD_AF(0, 3)
    LOAD_AF(1, 0) LOAD_AF(1, 1) LOAD_AF(1, 2) LOAD_AF(1, 3)
    LOAD_AF(2, 0) LOAD_AF(2, 1) LOAD_AF(2, 2) LOAD_AF(2, 3)
    LOAD_AF(3, 0) LOAD_AF(3, 1) LOAD_AF(3, 2) LOAD_AF(3, 3)
#undef LOAD_AF

    // ---- Consumer identity: thread 4r+g owns gate g of row r ----
    const int cg   = tid & 3;                 // gate: 0=i 1=f 2=g 3=o
    const int cr   = tid >> 2;                // row 0..127
    const int crow = cg * HDIM + cr;          // gate-row index in W_ih/b
    const float wihx = W_ih[2 * crow];
    const float wihy = W_ih[2 * crow + 1];
    const float bias = b_ih[crow] + b_hh[crow];
    const float gsc  = (cg == 2) ? 2.0f : 1.0f;   // tanh needs exp(-2x)
    float c = (cg == 0) ? c0[cr] : 0.0f;

    if (tid < HDIM) hbuf[0][tid] = (_Float16)h0[tid];
    __syncthreads();   // once, pre-loop

    const float2* xp = (const float2*)x;
    float2 xcur = xp[0];   // wave-uniform stream, all threads

    half8_t bf0 = (half8_t){0,0,0,0,0,0,0,0};
    half8_t bf1 = bf0, bf2 = bf0, bf3 = bf0;

    #pragma unroll 1
    for (int t = 0; t < S_LEN; ++t) {
        const int p  = t & 1;
        const int tn = (t + 1 < S_LEN) ? (t + 1) : (S_LEN - 1);
        float2 xnext = xp[tn];   // prefetch

        // ---- B fragments: col 0 = h, lanes {0,16,32,48} (R9-verbatim) ----
        if (m == 0) {
            const half8_t* hb = (const half8_t*)hbuf[p];
            bf0 = hb[quad];
            bf1 = hb[4 + quad];
            bf2 = hb[8 + quad];
            bf3 = hb[12 + quad];
        }
        f32x4 acc0 = {0.f, 0.f, 0.f, 0.f};
        f32x4 acc1 = {0.f, 0.f, 0.f, 0.f};
        f32x4 acc2 = {0.f, 0.f, 0.f, 0.f};
        f32x4 acc3 = {0.f, 0.f, 0.f, 0.f};
#define MFMA_TILE(i) \
        acc##i = __builtin_amdgcn_mfma_f32_16x16x32_f16(af_##i##_0, bf0, acc##i, 0, 0, 0); \
        acc##i = __builtin_amdgcn_mfma_f32_16x16x32_f16(af_##i##_1, bf1, acc##i, 0, 0, 0); \
        acc##i = __builtin_amdgcn_mfma_f32_16x16x32_f16(af_##i##_2, bf2, acc##i, 0, 0, 0); \
        acc##i = __builtin_amdgcn_mfma_f32_16x16x32_f16(af_##i##_3, bf3, acc##i, 0, 0, 0);
        MFMA_TILE(0) MFMA_TILE(1) MFMA_TILE(2) MFMA_TILE(3)
#undef MFMA_TILE

        // ---- Gate store, row-major [row][gate]: 4x b32, banks 2-way ----
        if (m == 0) {
#define STORE_TILE(i, accv) { \
            const int G = w * 64 + 16 * (i) + 4 * quad;       /* gate-row */ \
            float* gp = gates_sh + ((G & 127) << 2) + (G >> 7); \
            gp[0]  = accv[0]; \
            gp[4]  = accv[1]; \
            gp[8]  = accv[2]; \
            gp[12] = accv[3]; }
            STORE_TILE(0, acc0)
            STORE_TILE(1, acc1)
            STORE_TILE(2, acc2)
            STORE_TILE(3, acc3)
#undef STORE_TILE
        }
        block_sync_lds();  // barrier 1: gates visible

        // ---- Phase B: 512 threads, one gate-row each ----
        float gx = gates_sh[tid]                      // = [cr][cg], conflict-free
                 + fmaf(wihx, xcur.x, fmaf(wihy, xcur.y, bias));
        float v   = 1.0f / (1.0f + __expf(-gsc * gx));
        float act = fmaf(gsc, v, 1.0f - gsc);         // sigm, or tanh when cg==2
        // quad combine: lanes 4r+{0,1,2,3} are adjacent in one wave
        float actB = __shfl_xor(act, 1, 64);
        float actC = __shfl_xor(act, 2, 64);
        float actD = __shfl_xor(actB, 2, 64);
        if (cg == 0) {
            // act=gi, actB=gf, actC=gg, actD=go  (for row cr)
            c = fmaf(actB, c, act * actC);
            float h = actD * tanh_fast(c);
            _Float16 hf = (_Float16)h;
            hbuf[1 - p][cr] = hf;                           // next step's h
            h_hist[(size_t)t * HDIM + cr] = hf;             // floats past barrier
        }
        xcur = xnext;
        block_sync_lds();  // barrier 2: h_t visible
    }
}

// ================= Kernel 2: out[t] = tanh(h_t).W_out + b =================
__global__ __launch_bounds__(256)
void out_proj(const _Float16* __restrict__ h_hist,
              const float* __restrict__ W_out,
              const float* __restrict__ b_out,
              float* __restrict__ out)
{
    const int lane  = threadIdx.x & 63;
    const int gwave = (blockIdx.x * 256 + threadIdx.x) >> 6;
    const int nwave = (gridDim.x * 256) >> 6;

    const float wo0 = W_out[2 * lane + 0];
    const float wo1 = W_out[2 * lane + 1];
    const float bout = b_out[0];

    for (int t = gwave; t < S_LEN; t += nwave) {
        half2_t hv = ((const half2_t*)(h_hist + (size_t)t * HDIM))[lane];
        float p = tanh_fast((float)hv.x) * wo0 + tanh_fast((float)hv.y) * wo1;
        #pragma unroll
        for (int off = 32; off > 0; off >>= 1)
            p += __shfl_xor(p, off, 64);
        if (lane == 0) out[t] = p + bout;
    }
}

// ================= Fallback: fused single kernel (ws too small) ===========
#define H_HI_OFF 144
__global__ __launch_bounds__(1024)
__attribute__((amdgpu_waves_per_eu(4, 4)))
void lstm_seq_full(const float* __restrict__ x,
                   const float* __restrict__ h0,
                   const float* __restrict__ c0,
                   const float* __restrict__ W_ih,
                   const float* __restrict__ W_hh,
                   const float* __restrict__ b_ih,
                   const float* __restrict__ b_hh,
                   const float* __restrict__ W_out,
                   const float* __restrict__ b_out,
                   float* __restrict__ out)
{
    __shared__ __align__(16) unsigned char h_raw[2 * H_HI_OFF];
    __shared__ float gates_part[2 * 512];
    __shared__ float red_sh[2];

    const int tid  = threadIdx.x;
    const int j    = tid >> 1;
    const int half = tid & 1;

    const float2* wr2 = (const float2*)(W_hh + j * HDIM + half * 64);
#define WDEF(i) half2_t W##i; { float2 t = wr2[i]; \
        W##i.x = (_Float16)t.x; W##i.y = (_Float16)t.y; } \
        asm volatile("" : "+v"(W##i));
    WDEF(0)  WDEF(1)  WDEF(2)  WDEF(3)  WDEF(4)  WDEF(5)  WDEF(6)  WDEF(7)
    WDEF(8)  WDEF(9)  WDEF(10) WDEF(11) WDEF(12) WDEF(13) WDEF(14) WDEF(15)
    WDEF(16) WDEF(17) WDEF(18) WDEF(19) WDEF(20) WDEF(21) WDEF(22) WDEF(23)
    WDEF(24) WDEF(25) WDEF(26) WDEF(27) WDEF(28) WDEF(29) WDEF(30) WDEF(31)
#undef WDEF

    float wih0 = 0.0f, wih1 = 0.0f, bias = 0.0f;
    if (half == 0) {
        wih0 = W_ih[2 * j + 0];
        wih1 = W_ih[2 * j + 1];
        bias = b_ih[j] + b_hh[j];
    }

    float c = 0.0f, wout = 0.0f;
    _Float16* hw = (_Float16*)(h_raw + ((tid < 64) ? 2 * tid
                                                   : H_HI_OFF + 2 * (tid - 64)));
    if (tid < HDIM) {
        c = c0[tid];
        wout = W_out[tid];
        *hw = (_Float16)h0[tid];
    }
    const float bout = b_out[0];
    __syncthreads();

    const float2* xp = (const float2*)x;
    float2 xcur = xp[0];
    const half8_t* hp = (const half8_t*)(h_raw + half * H_HI_OFF);

    #pragma unroll 1
    for (int t = 0; t < S_LEN; ++t) {
        const int tn = (t + 1 < S_LEN) ? (t + 1) : (S_LEN - 1);
        float2 xnext = xp[tn];

        float a0 = fmaf(wih0, xcur.x, fmaf(wih1, xcur.y, bias));
        float a1 = 0.0f, a2 = 0.0f, a3 = 0.0f;

#define CHUNK(cc, w0_, w1_, w2_, w3_) {                         \
        half8_t hv = hp[cc];                                    \
        half2_t p0 = { hv[0], hv[1] };                          \
        half2_t p1 = { hv[2], hv[3] };                          \
        half2_t p2 = { hv[4], hv[5] };                          \
        half2_t p3 = { hv[6], hv[7] };                          \
        a0 = dot2(w0_, p0, a0);                                 \
        a1 = dot2(w1_, p1, a1);                                 \
        a2 = dot2(w2_, p2, a2);                                 \
        a3 = dot2(w3_, p3, a3); }
        CHUNK(0, W0,  W1,  W2,  W3)
        CHUNK(1, W4,  W5,  W6,  W7)
        CHUNK(2, W8,  W9,  W10, W11)
        CHUNK(3, W12, W13, W14, W15)
        CHUNK(4, W16, W17, W18, W19)
        CHUNK(5, W20, W21, W22, W23)
        CHUNK(6, W24, W25, W26, W27)
        CHUNK(7, W28, W29, W30, W31)
#undef CHUNK

        gates_part[half * 512 + j] = (a0 + a1) + (a2 + a3);
        __syncthreads();

        if (tid < HDIM) {
            float gi = sigm(gates_part[tid]            + gates_part[tid + 512]);
            float gf = sigm(gates_part[tid + 128]      + gates_part[tid + 640]);
            float gg = tanh_fast(gates_part[tid + 256] + gates_part[tid + 768]);
            float go = sigm(gates_part[tid + 384]      + gates_part[tid + 896]);
            c = fmaf(gf, c, gi * gg);
            float h = go * tanh_fast(c);
            *hw = (_Float16)h;

            float p = tanh_fast(h) * wout;
            #pragma unroll
            for (int off = 32; off > 0; off >>= 1)
                p += __shfl_xor(p, off, 64);
            if ((tid & 63) == 0) red_sh[tid >> 6] = p;
        }
        __syncthreads();

        if (tid == 0) out[t] = red_sh[0] + red_sh[1] + bout;
        xcur = xnext;
    }
}

extern "C" void kernel_launch(void* const* d_in, const int* in_sizes, int n_in,
                              void* d_out, int out_size, void* d_ws, size_t ws_size,
                              hipStream_t stream) {
    const float* x     = (const float*)d_in[0];
    const float* h0    = (const float*)d_in[1];
    const float* c0    = (const float*)d_in[2];
    const float* W_ih  = (const float*)d_in[3];
    const float* W_hh  = (const float*)d_in[4];
    const float* b_ih  = (const float*)d_in[5];
    const float* b_hh  = (const float*)d_in[6];
    const float* W_out = (const float*)d_in[7];
    const float* b_out = (const float*)d_in[8];

    const size_t need = (size_t)S_LEN * HDIM * sizeof(_Float16);  // 16 MiB
    if (ws_size >= need) {
        _Float16* h_hist = (_Float16*)d_ws;
        lstm_seq_mfma<<<dim3(1), dim3(512), 0, stream>>>(
            x, h0, c0, W_ih, W_hh, b_ih, b_hh, h_hist);
        out_proj<<<dim3(1024), dim3(256), 0, stream>>>(
            h_hist, W_out, b_out, (float*)d_out);
    } else {
        lstm_seq_full<<<dim3(1), dim3(1024), 0, stream>>>(
            x, h0, c0, W_ih, W_hh, b_ih, b_hh, W_out, b_out, (float*)d_out);
    }
}